// Round 12
// baseline (222.107 us; speedup 1.0000x reference)
//
#include <hip/hip_runtime.h>

#define N_NODES 100000
#define N_EDGES 1600000
#define D_IN 128
#define D_HID 64

#define BKT_SHIFT 8
#define BKT_NODES 256
#define NB 391          // ceil(N_NODES / 256) buckets
#define NBLK 392        // scatter blocks
#define SLOT 32         // slots per (bucket,block): Poisson(10.4), +6.7 sigma
#define SEG4 (SLOT / 4) // uint4s per segment
#define REG4 (NBLK * SEG4)   // uint4s per bucket region = 3136
#define BKT_CAP 5120    // per-bucket capacity (mean 4092)
#define OVF_CAP 8192

typedef __attribute__((ext_vector_type(8))) short bf16x8;
typedef __attribute__((ext_vector_type(4))) float f32x4;

__device__ __forceinline__ unsigned short f2b(float f) {
    union { float f; unsigned u; } c; c.f = f;
    unsigned r = (c.u + 0x7FFFu + ((c.u >> 16) & 1u)) >> 16;   // RNE
    return (unsigned short)r;
}
__device__ __forceinline__ float blo(unsigned u) { return __uint_as_float(u << 16); }
__device__ __forceinline__ float bhi(unsigned u) { return __uint_as_float(u & 0xffff0000u); }

// ================= one-pass partition, bucket-major fixed-slot regions ==============
// code = (src << 8) | (dst & 255); region pairs[bucket][block][SLOT]
// First 32 blocks also convert W1 -> bf16 transposed (absorbs old k_prep).
__global__ __launch_bounds__(256) void k_escatter(const int* __restrict__ src,
                                                  const int* __restrict__ dst,
                                                  const float* __restrict__ W1,
                                                  unsigned short* __restrict__ w1t,
                                                  int* __restrict__ pairs,
                                                  int* __restrict__ cnt_blk,
                                                  int* __restrict__ ovf_cnt,
                                                  int2* __restrict__ ovf, int E) {
    __shared__ int lcur[NB];
    int tid = threadIdx.x;
    if (blockIdx.x < 32) {                     // W1 is [128][64] -> w1t[f][k]
        int t = blockIdx.x * 256 + tid;
        int k = t >> 6, f = t & 63;
        w1t[f * D_IN + k] = f2b(W1[t]);
    }
    for (int t = tid; t < NB; t += 256) lcur[t] = 0;
    __syncthreads();
    int chunk = (E + NBLK - 1) / NBLK;
    int beg = blockIdx.x * chunk;
    int end = min(beg + chunk, E);
    for (int e = beg + tid; e < end; e += 256) {
        int d = dst[e], s = src[e];
        int bk = d >> BKT_SHIFT;
        int slot = atomicAdd(&lcur[bk], 1);
        if (slot < SLOT)
            pairs[(bk * NBLK + blockIdx.x) * SLOT + slot] = (s << BKT_SHIFT) | (d & (BKT_NODES - 1));
        else {
            int o = atomicAdd(ovf_cnt, 1);
            if (o < OVF_CAP) ovf[o] = make_int2(s, d);
        }
    }
    __syncthreads();
    for (int t = tid; t < NB; t += 256)
        cnt_blk[t * NBLK + blockIdx.x] = min(lcur[t], SLOT);
}

// ================= per-bucket sort: ONE guarded global read + LDS staging ===========
__global__ __launch_bounds__(256) void k_bsort(const uint4* __restrict__ pairs4,
                                               const int* __restrict__ cnt_blk,
                                               const int* __restrict__ ovf_cnt,
                                               const int2* __restrict__ ovf,
                                               int* __restrict__ srcs_sorted,
                                               int* __restrict__ row_start,
                                               int* __restrict__ row_end,
                                               float* __restrict__ dis, int n) {
    __shared__ int segc[NBLK];
    __shared__ int segb[NBLK];          // staging base per segment
    __shared__ int cnt[BKT_NODES];
    __shared__ int exc[BKT_NODES];
    __shared__ int staged[BKT_CAP];
    __shared__ int sorted[BKT_CAP];
    __shared__ int nE_sh;
    int b = blockIdx.x;
    int tid = threadIdx.x;
    int node0 = b << BKT_SHIFT;
    int ocnt = min(ovf_cnt[0], OVF_CAP);
    const uint4* region = pairs4 + (size_t)b * REG4;

    for (int i = tid; i < NBLK; i += 256) segc[i] = cnt_blk[b * NBLK + i];
    cnt[tid] = 0;
    __syncthreads();

    if (tid < 64) {   // wave-0 exclusive scan of segc[392] -> segb
        int run = 0;
        for (int c = 0; c < NBLK; c += 64) {
            int idx = c + tid;
            int v = (idx < NBLK) ? segc[idx] : 0;
            int inc = v;
            for (int off = 1; off < 64; off <<= 1) {
                int t2 = __shfl_up(inc, off);
                if (tid >= off) inc += t2;
            }
            if (idx < NBLK) segb[idx] = run + inc - v;
            run += __shfl(inc, 63);
        }
        if (tid == 63) nE_sh = run;
    }
    __syncthreads();

    // single guarded read; compact valid codes into LDS staged[]
    for (int i4 = tid; i4 < REG4; i4 += 256) {
        int seg = i4 >> 3;
        int c = segc[seg];
        int k = (i4 & 7) * 4;
        if (k < c) {
            uint4 v = region[i4];
            int base = segb[seg] + k;
            if (base < BKT_CAP)                  staged[base]     = v.x;
            if (k + 1 < c && base + 1 < BKT_CAP) staged[base + 1] = v.y;
            if (k + 2 < c && base + 2 < BKT_CAP) staged[base + 2] = v.z;
            if (k + 3 < c && base + 3 < BKT_CAP) staged[base + 3] = v.w;
        }
    }
    __syncthreads();
    int nE = min(nE_sh, BKT_CAP);

    // histogram from LDS
    for (int k = tid; k < nE; k += 256)
        atomicAdd(&cnt[staged[k] & (BKT_NODES - 1)], 1);
    for (int k = tid; k < ocnt; k += 256) {
        int2 e = ovf[k];
        if ((e.y >> BKT_SHIFT) == b) atomicAdd(&cnt[e.y & (BKT_NODES - 1)], 1);
    }
    __syncthreads();

    if (tid < 64) {   // wave-0 exclusive scan of cnt[256]
        int run = 0;
        for (int c = 0; c < BKT_NODES; c += 64) {
            int v = cnt[c + tid];
            int inc = v;
            for (int off = 1; off < 64; off <<= 1) {
                int t2 = __shfl_up(inc, off);
                if (tid >= off) inc += t2;
            }
            exc[c + tid] = run + inc - v;
            run += __shfl(inc, 63);
        }
    }
    __syncthreads();

    int node = node0 + tid;
    int tot = exc[BKT_NODES - 1] + cnt[BKT_NODES - 1];   // nE + this bucket's ovf
    if (node < n) {
        int rs = b * BKT_CAP + exc[tid];
        row_start[node] = rs;
        row_end[node] = rs + cnt[tid];
        dis[node] = rsqrtf((float)cnt[tid] + 1.0f);
    }
    __syncthreads();
    cnt[tid] = exc[tid];          // repurpose as per-node cursor
    __syncthreads();

    // place from LDS
    for (int k = tid; k < nE; k += 256) {
        int pk = staged[k];
        int p = atomicAdd(&cnt[pk & (BKT_NODES - 1)], 1);
        sorted[p] = pk >> BKT_SHIFT;
    }
    for (int k = tid; k < ocnt; k += 256) {
        int2 e = ovf[k];
        if ((e.y >> BKT_SHIFT) == b) {
            int p = atomicAdd(&cnt[e.y & (BKT_NODES - 1)], 1);
            sorted[p] = e.x;
        }
    }
    __syncthreads();

    // coalesced write-out
    int gbase = b * BKT_CAP;
    int nTot = min(tot, BKT_CAP);
    for (int k = tid; k < nTot; k += 256)
        srcs_sorted[gbase + k] = sorted[k];
}

// ================= layer 1 GEMM via bf16 MFMA, epilogue pre-scales by dis ===========
#define LS 136
__global__ __launch_bounds__(256) void k_gemm1(const float* __restrict__ x,
                                               const uint4* __restrict__ w1t4,
                                               const float* __restrict__ dis,
                                               unsigned short* __restrict__ h1s, int n) {
    __shared__ unsigned short xs[64 * LS];
    __shared__ unsigned short ws[64 * LS];
    int tid = threadIdx.x;
    int node0 = blockIdx.x * 64;

#pragma unroll
    for (int it = 0; it < 4; ++it) {
        int e = tid + it * 256;
        int f = e >> 4, c = e & 15;
        *(uint4*)&ws[f * LS + c * 8] = w1t4[e];
    }
#pragma unroll
    for (int it = 0; it < 8; ++it) {
        int e4 = tid + it * 256;
        int node = e4 >> 5;
        int k = (e4 & 31) * 4;
        float4 v = make_float4(0.f, 0.f, 0.f, 0.f);
        if (node0 + node < n)
            v = ((const float4*)x)[((size_t)(node0 + node) * D_IN + k) >> 2];
        uint2 u;
        u.x = (unsigned)f2b(v.x) | ((unsigned)f2b(v.y) << 16);
        u.y = (unsigned)f2b(v.z) | ((unsigned)f2b(v.w) << 16);
        *(uint2*)&xs[node * LS + k] = u;
    }
    __syncthreads();

    int wv = tid >> 6;
    int lane = tid & 63;
    int m16 = lane & 15;
    int q = lane >> 4;

    bf16x8 afrag[4];
#pragma unroll
    for (int ks = 0; ks < 4; ++ks)
        afrag[ks] = *(const bf16x8*)&xs[(wv * 16 + m16) * LS + ks * 32 + q * 8];

    f32x4 acc[4];
#pragma unroll
    for (int ft = 0; ft < 4; ++ft) acc[ft] = (f32x4){0.f, 0.f, 0.f, 0.f};

#pragma unroll
    for (int ft = 0; ft < 4; ++ft)
#pragma unroll
        for (int ks = 0; ks < 4; ++ks) {
            bf16x8 bfrag = *(const bf16x8*)&ws[(ft * 16 + m16) * LS + ks * 32 + q * 8];
            acc[ft] = __builtin_amdgcn_mfma_f32_16x16x32_bf16(afrag[ks], bfrag, acc[ft], 0, 0, 0);
        }

#pragma unroll
    for (int r = 0; r < 4; ++r) {
        int node = node0 + wv * 16 + q * 4 + r;
        if (node < n) {
            float d = dis[node];
#pragma unroll
            for (int ft = 0; ft < 4; ++ft)
                h1s[(size_t)node * D_HID + ft * 16 + m16] = f2b(acc[ft][r] * d);
        }
    }
}

// ================= fused agg1 + bias + ReLU + dot(W2) -> zd = z*dis =================
__global__ __launch_bounds__(256) void k_gather1(const int* __restrict__ srcs,
                                                 const int* __restrict__ row_start,
                                                 const int* __restrict__ row_end,
                                                 const float* __restrict__ dis,
                                                 const uint4* __restrict__ h4,
                                                 const float* __restrict__ b1,
                                                 const float* __restrict__ W2,
                                                 float* __restrict__ zd, int n) {
    int i = blockIdx.x * 8 + (threadIdx.x >> 5);     // node for this half-wave
    int lane = threadIdx.x & 63;
    int g = (lane >> 3) & 3;  // edge group within half-wave
    int m8 = lane & 7;        // feature block (feats 8*m8 .. 8*m8+7)
    float dd = dis[i];

    float a0, a1, a2, a3, a4, a5, a6, a7;
    {   // self-loop handled by group 0
        uint4 u = h4[(unsigned)i * 8u + m8];
        float w = (g == 0) ? 1.f : 0.f;
        a0 = w * blo(u.x); a1 = w * bhi(u.x);
        a2 = w * blo(u.y); a3 = w * bhi(u.y);
        a4 = w * blo(u.z); a5 = w * bhi(u.z);
        a6 = w * blo(u.w); a7 = w * bhi(u.w);
    }

#define ACC(u) { a0 += blo(u.x); a1 += bhi(u.x); a2 += blo(u.y); a3 += bhi(u.y); \
                 a4 += blo(u.z); a5 += bhi(u.z); a6 += blo(u.w); a7 += bhi(u.w); }
    int end = row_end[i];
    int j = row_start[i] + g;
    for (; j + 4 < end; j += 8) {               // unroll x2: two loads in flight
        int s0 = srcs[j];
        int s1 = srcs[j + 4];
        uint4 u0 = h4[(unsigned)s0 * 8u + m8];
        uint4 u1 = h4[(unsigned)s1 * 8u + m8];
        ACC(u0); ACC(u1);
    }
    if (j < end) {
        int s0 = srcs[j];
        uint4 u0 = h4[(unsigned)s0 * 8u + m8];
        ACC(u0);
    }
#undef ACC

#pragma unroll
    for (int off = 8; off < 32; off <<= 1) {
        a0 += __shfl_xor(a0, off); a1 += __shfl_xor(a1, off);
        a2 += __shfl_xor(a2, off); a3 += __shfl_xor(a3, off);
        a4 += __shfl_xor(a4, off); a5 += __shfl_xor(a5, off);
        a6 += __shfl_xor(a6, off); a7 += __shfl_xor(a7, off);
    }
    float4 ba = ((const float4*)b1)[m8 * 2];
    float4 bb = ((const float4*)b1)[m8 * 2 + 1];
    float4 wa = ((const float4*)W2)[m8 * 2];
    float4 wb = ((const float4*)W2)[m8 * 2 + 1];
    float v = fmaxf(fmaf(dd, a0, ba.x), 0.f) * wa.x + fmaxf(fmaf(dd, a1, ba.y), 0.f) * wa.y
            + fmaxf(fmaf(dd, a2, ba.z), 0.f) * wa.z + fmaxf(fmaf(dd, a3, ba.w), 0.f) * wa.w
            + fmaxf(fmaf(dd, a4, bb.x), 0.f) * wb.x + fmaxf(fmaf(dd, a5, bb.y), 0.f) * wb.y
            + fmaxf(fmaf(dd, a6, bb.z), 0.f) * wb.z + fmaxf(fmaf(dd, a7, bb.w), 0.f) * wb.w;
#pragma unroll
    for (int off = 1; off < 8; off <<= 1) v += __shfl_xor(v, off);
    if ((lane & 31) == 0) zd[i] = v * dd;
}

// ================= agg2 (2 nodes/wave) + fused padded output =================
__global__ __launch_bounds__(256) void k_gather2(const int* __restrict__ srcs,
                                                 const int* __restrict__ row_start,
                                                 const int* __restrict__ row_end,
                                                 const float* __restrict__ dis,
                                                 const float* __restrict__ zd,
                                                 const float* __restrict__ b2,
                                                 float* __restrict__ out, int n) {
    int i = blockIdx.x * 8 + (threadIdx.x >> 5);
    int l = threadIdx.x & 31;
    float acc = 0.f;
    int beg = row_start[i], end = row_end[i];
    for (int j = beg + l; j < end; j += 32)
        acc += zd[srcs[j]];
#pragma unroll
    for (int off = 1; off < 32; off <<= 1) acc += __shfl_xor(acc, off);
    float y = (acc + zd[i]) * dis[i] + b2[0];
    float4 v = make_float4(0.f, 0.f, 0.f, 0.f);
    if (l == 0) v.x = y;
    ((float4*)out)[(size_t)i * 32 + l] = v;
}

extern "C" void kernel_launch(void* const* d_in, const int* in_sizes, int n_in,
                              void* d_out, int out_size, void* d_ws, size_t ws_size,
                              hipStream_t stream) {
    const float* x  = (const float*)d_in[0];
    const int*   ei = (const int*)d_in[1];   // [2, E] int32
    const float* W1 = (const float*)d_in[2];
    const float* b1 = (const float*)d_in[3];
    const float* W2 = (const float*)d_in[4];
    const float* b2 = (const float*)d_in[5];
    float* out = (float*)d_out;

    const int n = N_NODES;
    const int E = N_EDGES;
    const int* src = ei;
    const int* dst = ei + E;

    // ws: pairs int[NB*NBLK*SLOT] (19.6MB) | cnt_blk int[NB*NBLK] (613KB) |
    //     srcs_sorted int[NB*BKT_CAP] (8MB) | row_start[n] | row_end[n] |
    //     ovf_cnt[4] | ovf int2[OVF_CAP] | dis f[n] | h1s ushort[n*64] (12.8MB) |
    //     w1t ushort[8192] | zd f[n]
    int* pairs       = (int*)d_ws;
    int* cnt_blk     = pairs + (size_t)NB * NBLK * SLOT;
    int* srcs_sorted = cnt_blk + (size_t)NB * NBLK;
    int* row_start   = srcs_sorted + (size_t)NB * BKT_CAP;
    int* row_end     = row_start + n;
    int* ovf_cnt     = row_end + n;
    int2* ovf        = (int2*)(ovf_cnt + 4);
    float* dis       = (float*)(ovf + OVF_CAP);
    unsigned short* h1s = (unsigned short*)(dis + n);
    unsigned short* w1t = h1s + (size_t)n * D_HID;
    float* zd        = (float*)(w1t + D_IN * D_HID);

    hipMemsetAsync(ovf_cnt, 0, 4, stream);
    k_escatter<<<NBLK, 256, 0, stream>>>(src, dst, W1, w1t, pairs, cnt_blk, ovf_cnt, ovf, E);
    k_bsort<<<NB, 256, 0, stream>>>((const uint4*)pairs, cnt_blk, ovf_cnt, ovf,
                                    srcs_sorted, row_start, row_end, dis, n);

    k_gemm1<<<(n + 63) / 64, 256, 0, stream>>>(x, (const uint4*)w1t, dis, h1s, n);

    k_gather1<<<(n + 7) / 8, 256, 0, stream>>>(srcs_sorted, row_start, row_end, dis,
                                               (const uint4*)h1s, b1, W2, zd, n);
    k_gather2<<<(n + 7) / 8, 256, 0, stream>>>(srcs_sorted, row_start, row_end, dis,
                                               zd, b2, out, n);
}